// Round 2
// baseline (426.603 us; speedup 1.0000x reference)
//
#include <hip/hip_runtime.h>

typedef unsigned short u16;
typedef unsigned int u32;

typedef __bf16 bf16x8 __attribute__((ext_vector_type(8)));
typedef float f32x4 __attribute__((ext_vector_type(4)));

// bf16 round-to-nearest-even from f32
__device__ __forceinline__ u16 f2bf(float f) {
    u32 u = __float_as_uint(f);
    return (u16)((u + 0x7fffu + ((u >> 16) & 1u)) >> 16);
}

__device__ __forceinline__ float rowreduce64(float s) {
#pragma unroll
    for (int off = 32; off > 0; off >>= 1) s += __shfl_xor(s, off, 64);
    return s;
}

// +8 bf16 pad: row stride 1040 B = 260 dwords, 260 % 32 = 4 -> rows r and r+8
// alias a bank pair -> 2-way conflict only (free per m136).
constexpr int LDK = 520;

// Fully fused, ZERO-workspace kernel.
// grid: (tTiles=8, b=32) = 256 blocks = 1 block/CU. block = 512 thr = 8 waves.
// Phase 1: vm[32 t][512 d] = mean_n(normalize(v[b,n,t,:])) -> bf16 LDS tile.
// Phase 2: 8 chunks of 64 c: normalize t_feat rows on the fly (L2-resident,
//          recompute per block), bf16 LDS, 16x16x32 MFMA, store out directly.
__global__ __launch_bounds__(512, 2) void fused_kernel(
    const float* __restrict__ v,
    const float* __restrict__ tf,
    float* __restrict__ out,
    const int* __restrict__ splitp)
{
    const int b    = blockIdx.y;
    const int t0   = blockIdx.x * 32;
    const int tid  = threadIdx.x;
    const int w    = tid >> 6;    // wave 0..7
    const int lane = tid & 63;
    const int quad = lane >> 4;
    const int l15  = lane & 15;
    const int split = *splitp;

    __shared__ u16 At[64 * LDK];  // tn c-chunk  (66.6 KB)
    __shared__ u16 Bt[32 * LDK];  // vm t-tile   (33.3 KB)   total ~97.5 KB -> 1 blk/CU

    // ---------------- phase 1: v-mean tile ----------------
    // wave w owns t-rows w*4 .. w*4+3; each accumulates over n=0..15.
    for (int tt = 0; tt < 4; tt++) {
        const int tl = w * 4 + tt;
        float acc[8];
#pragma unroll
        for (int i = 0; i < 8; i++) acc[i] = 0.f;
#pragma unroll 4
        for (int n = 0; n < 16; n++) {
            const float* row = v + (((size_t)(b * 16 + n) * 256 + (t0 + tl)) * 512) + lane * 8;
            float4 x0 = *reinterpret_cast<const float4*>(row);
            float4 x1 = *reinterpret_cast<const float4*>(row + 4);
            float s = x0.x*x0.x + x0.y*x0.y + x0.z*x0.z + x0.w*x0.w
                    + x1.x*x1.x + x1.y*x1.y + x1.z*x1.z + x1.w*x1.w;
            s = rowreduce64(s);
            float inv = 1.0f;
            if (split == 1) inv = 1.0f / fmaxf(sqrtf(s), 1e-12f);
            acc[0] += x0.x*inv; acc[1] += x0.y*inv;
            acc[2] += x0.z*inv; acc[3] += x0.w*inv;
            acc[4] += x1.x*inv; acc[5] += x1.y*inv;
            acc[6] += x1.z*inv; acc[7] += x1.w*inv;
        }
        uint4 pk;
        pk.x = (u32)f2bf(acc[0]*0.0625f) | ((u32)f2bf(acc[1]*0.0625f) << 16);
        pk.y = (u32)f2bf(acc[2]*0.0625f) | ((u32)f2bf(acc[3]*0.0625f) << 16);
        pk.z = (u32)f2bf(acc[4]*0.0625f) | ((u32)f2bf(acc[5]*0.0625f) << 16);
        pk.w = (u32)f2bf(acc[6]*0.0625f) | ((u32)f2bf(acc[7]*0.0625f) << 16);
        *reinterpret_cast<uint4*>(&Bt[tl * LDK + lane * 8]) = pk;
    }

    // ---------------- phase 2: tn chunks + MFMA ----------------
    const int wm = w & 3;     // c dir: 4 x 16
    const int wn = w >> 2;    // t dir: 2 x 16
    const float sc = 1.0f / 0.07f;
    float* ob = out + (size_t)b * 131072;  // 512*256

    for (int cc = 0; cc < 8; cc++) {
        // stage + normalize 64 t_feat rows: wave w does rows w*8 .. w*8+7
#pragma unroll
        for (int rr = 0; rr < 8; rr++) {
            const int r = w * 8 + rr;
            const float* rp = tf + (size_t)(cc * 64 + r) * 512 + lane * 8;
            float4 x0 = *reinterpret_cast<const float4*>(rp);
            float4 x1 = *reinterpret_cast<const float4*>(rp + 4);
            float s = x0.x*x0.x + x0.y*x0.y + x0.z*x0.z + x0.w*x0.w
                    + x1.x*x1.x + x1.y*x1.y + x1.z*x1.z + x1.w*x1.w;
            s = rowreduce64(s);
            float inv = 1.0f;
            if (split == 1) inv = 1.0f / fmaxf(sqrtf(s), 1e-12f);
            uint4 pk;
            pk.x = (u32)f2bf(x0.x*inv) | ((u32)f2bf(x0.y*inv) << 16);
            pk.y = (u32)f2bf(x0.z*inv) | ((u32)f2bf(x0.w*inv) << 16);
            pk.z = (u32)f2bf(x1.x*inv) | ((u32)f2bf(x1.y*inv) << 16);
            pk.w = (u32)f2bf(x1.z*inv) | ((u32)f2bf(x1.w*inv) << 16);
            *reinterpret_cast<uint4*>(&At[r * LDK + lane * 8]) = pk;
        }
        __syncthreads();   // At ready (and, on cc==0, Bt from phase 1)

        f32x4 acc = {0.f, 0.f, 0.f, 0.f};
#pragma unroll
        for (int kk = 0; kk < 512; kk += 32) {
            bf16x8 af = *reinterpret_cast<const bf16x8*>(
                &At[(wm * 16 + l15) * LDK + kk + quad * 8]);
            bf16x8 bf = *reinterpret_cast<const bf16x8*>(
                &Bt[(wn * 16 + l15) * LDK + kk + quad * 8]);
            acc = __builtin_amdgcn_mfma_f32_16x16x32_bf16(af, bf, acc, 0, 0, 0);
        }
        __syncthreads();   // all LDS reads done before next chunk overwrites At

#pragma unroll
        for (int r = 0; r < 4; r++) {
            const int c = cc * 64 + wm * 16 + quad * 4 + r;
            ob[c * 256 + (t0 + wn * 16 + l15)] = acc[r] * sc;
        }
    }
}

extern "C" void kernel_launch(void* const* d_in, const int* in_sizes, int n_in,
                              void* d_out, int out_size, void* d_ws, size_t ws_size,
                              hipStream_t stream) {
    const float* v_feat = (const float*)d_in[0];   // (32,16,256,512) f32
    const float* t_feat = (const float*)d_in[1];   // (512,512) f32
    const int*   splitp = (const int*)d_in[2];
    float* out = (float*)d_out;                    // (32,512,256) f32

    (void)d_ws; (void)ws_size;  // ZERO workspace use — no intermediate buffers

    fused_kernel<<<dim3(8, 32), dim3(512), 0, stream>>>(v_feat, t_feat, out, splitp);
}